// Round 1
// baseline (1560.896 us; speedup 1.0000x reference)
//
#include <hip/hip_runtime.h>

#define S_LEN 1024
#define NHEAD 32
#define HSZ   128
#define HIDN  4096
#define NQKV  12288
#define T_TOK 4096
// 128^-0.5 * log2(e)
#define ATT_SCALE 0.12751743f

typedef __bf16 bf16x8 __attribute__((ext_vector_type(8)));
typedef float  floatx4 __attribute__((ext_vector_type(4)));

union B8U { uint4 u; bf16x8 v; };

__device__ __forceinline__ unsigned short f2bf(float x) {
  unsigned int u = __float_as_uint(x);
  unsigned int r = (u + 0x7FFFu + ((u >> 16) & 1u)) >> 16;
  return (unsigned short)r;
}

__device__ __forceinline__ void gload_lds16(const void* g, void* l) {
  __builtin_amdgcn_global_load_lds(
      (__attribute__((address_space(1))) void*)(unsigned long long)g,
      (__attribute__((address_space(3))) void*)l, 16, 0, 0);
}

__device__ __forceinline__ bf16x8 lds_frag(const unsigned short* p) {
  return *reinterpret_cast<const bf16x8*>(p);
}

// ---------------- cast fp32 -> bf16 (contiguous) ----------------
__global__ __launch_bounds__(256) void cast_bf16_kernel(
    const float* __restrict__ in, unsigned short* __restrict__ out, int n) {
  int idx = (blockIdx.x * 256 + threadIdx.x) * 4;
  if (idx >= n) return;
  float4 f = *reinterpret_cast<const float4*>(in + idx);
  ushort4 o;
  o.x = f2bf(f.x); o.y = f2bf(f.y); o.z = f2bf(f.z); o.w = f2bf(f.w);
  *reinterpret_cast<ushort4*>(out + idx) = o;
}

// ---------------- transpose-cast: w (K,N) fp32 -> wt (N,K) bf16 ----------------
__global__ __launch_bounds__(256) void tcast_kernel(
    const float* __restrict__ w, unsigned short* __restrict__ wt, int K, int N) {
  __shared__ float tile[32][33];
  int n0 = blockIdx.x * 32, k0 = blockIdx.y * 32;
  int tx = threadIdx.x, ty = threadIdx.y;
#pragma unroll
  for (int i = 0; i < 32; i += 8)
    tile[ty + i][tx] = w[(size_t)(k0 + ty + i) * N + n0 + tx];
  __syncthreads();
#pragma unroll
  for (int i = 0; i < 32; i += 8)
    wt[(size_t)(n0 + ty + i) * K + k0 + tx] = f2bf(tile[tx][ty + i]);
}

// ---------------- GEMM: C(M,N) fp32 = A(M,K)bf16 * Bt(N,K)bf16 + bias ----------------
// m97 structure: 128x128 tile, BK=32, 4 waves in 2x2, 4x4 16x16x32 MFMA per wave.
__global__ __launch_bounds__(256) void gemm_bt(
    const unsigned short* __restrict__ A, const unsigned short* __restrict__ Bt,
    const float* __restrict__ bias, float* __restrict__ C, int M, int N, int K) {
  __shared__ __align__(16) unsigned short ldsA[128 * 32];
  __shared__ __align__(16) unsigned short ldsB[128 * 32];
  const int tid = threadIdx.x;
  const int lane = tid & 63, w = tid >> 6;
  const int m = lane & 15, quad = lane >> 4;
  const int wm = w >> 1, wn = w & 1;
  const int tM = blockIdx.y * 128, tN = blockIdx.x * 128;

  floatx4 acc[4][4] = {};
  const unsigned short* pA = A + (size_t)tM * K;
  const unsigned short* pB = Bt + (size_t)tN * K;
  const int r0 = tid >> 2, c0 = (tid & 3) * 8;

  for (int k0 = 0; k0 < K; k0 += 32) {
    gload_lds16(pA + (size_t)r0 * K + k0 + c0,        &ldsA[tid * 8]);
    gload_lds16(pA + (size_t)(r0 + 64) * K + k0 + c0, &ldsA[(tid + 256) * 8]);
    gload_lds16(pB + (size_t)r0 * K + k0 + c0,        &ldsB[tid * 8]);
    gload_lds16(pB + (size_t)(r0 + 64) * K + k0 + c0, &ldsB[(tid + 256) * 8]);
    __syncthreads();
    bf16x8 af[4], bfr[4];
#pragma unroll
    for (int i = 0; i < 4; ++i)
      af[i] = lds_frag(&ldsA[(wm * 64 + i * 16 + m) * 32 + quad * 8]);
#pragma unroll
    for (int j = 0; j < 4; ++j)
      bfr[j] = lds_frag(&ldsB[(wn * 64 + j * 16 + m) * 32 + quad * 8]);
#pragma unroll
    for (int i = 0; i < 4; ++i)
#pragma unroll
      for (int j = 0; j < 4; ++j)
        acc[i][j] = __builtin_amdgcn_mfma_f32_16x16x32_bf16(af[i], bfr[j], acc[i][j], 0, 0, 0);
    __syncthreads();
  }
#pragma unroll
  for (int i = 0; i < 4; ++i) {
    int row = tM + wm * 64 + i * 16 + quad * 4;
#pragma unroll
    for (int j = 0; j < 4; ++j) {
      int col = tN + wn * 64 + j * 16 + m;
      float bb = bias ? bias[col] : 0.0f;
      float* cp = C + (size_t)row * N + col;
#pragma unroll
      for (int r = 0; r < 4; ++r)
        cp[(size_t)r * N] = acc[i][j][r] + bb;
    }
  }
}

// ---------------- rope + kv scatter ----------------
__global__ __launch_bounds__(256) void rope_kernel(
    const float* __restrict__ qkv, const float* __restrict__ cosb,
    const float* __restrict__ sinb, const int* __restrict__ slots,
    unsigned short* __restrict__ Qb, unsigned short* __restrict__ Kb,
    float* __restrict__ KvK, float* __restrict__ KvV) {
  const int t = blockIdx.x, tid = threadIdx.x;
  const size_t base = (size_t)t * NQKV;
  const int slot = slots[t];
  const size_t obase = (size_t)t * 4096;
  const size_t cbase = (size_t)slot * 4096;
  // rotary dims (pairs r, r+32), q and k
  for (int idx = tid; idx < NHEAD * 32; idx += 256) {
    int hh = idx >> 5, r = idx & 31;
    float c = cosb[t * 32 + r], sn = sinb[t * 32 + r];
    int d0 = hh * 128 + r;
    float q1 = qkv[base + d0], q2 = qkv[base + d0 + 32];
    float k1 = qkv[base + 4096 + d0], k2 = qkv[base + 4096 + d0 + 32];
    float qr1 = q1 * c - q2 * sn, qr2 = q2 * c + q1 * sn;
    float kr1 = k1 * c - k2 * sn, kr2 = k2 * c + k1 * sn;
    Qb[obase + d0]      = f2bf(qr1 * ATT_SCALE);
    Qb[obase + d0 + 32] = f2bf(qr2 * ATT_SCALE);
    Kb[obase + d0]      = f2bf(kr1);
    Kb[obase + d0 + 32] = f2bf(kr2);
    KvK[cbase + d0] = kr1; KvK[cbase + d0 + 32] = kr2;
  }
  // passthrough dims 64..127 of q,k
  for (int idx = tid; idx < NHEAD * 64; idx += 256) {
    int hh = idx >> 6, p = idx & 63;
    int d = hh * 128 + 64 + p;
    float q = qkv[base + d], k = qkv[base + 4096 + d];
    Qb[obase + d] = f2bf(q * ATT_SCALE);
    Kb[obase + d] = f2bf(k);
    KvK[cbase + d] = k;
  }
  // v -> cache
  for (int idx = tid; idx < NHEAD * 128; idx += 256)
    KvV[cbase + idx] = qkv[base + 8192 + idx];
}

// ---------------- V transpose: qkv v-part (b,s,h,d) fp32 -> Vt (bh, d, s) bf16 ----------------
__global__ __launch_bounds__(256) void vtrans_kernel(
    const float* __restrict__ qkv, unsigned short* __restrict__ vt) {
  __shared__ float tile[32][33];
  int s0 = blockIdx.x * 32, d0 = blockIdx.y * 32, bh = blockIdx.z;
  int b = bh >> 5, h = bh & 31;
  int tx = threadIdx.x, ty = threadIdx.y;
#pragma unroll
  for (int i = 0; i < 32; i += 8)
    tile[ty + i][tx] =
        qkv[(size_t)(b * S_LEN + s0 + ty + i) * NQKV + 8192 + h * 128 + d0 + tx];
  __syncthreads();
#pragma unroll
  for (int i = 0; i < 32; i += 8)
    vt[(size_t)(bh * 128 + d0 + ty + i) * S_LEN + s0 + tx] = f2bf(tile[tx][ty + i]);
}

// ---------------- MFMA flash attention ----------------
// grid (S/64, B*NH). 4 waves, wave w owns q rows qb*64+w*16 .. +15. 32-key tiles.
__global__ __launch_bounds__(256) void attn_kernel(
    const unsigned short* __restrict__ Q, const unsigned short* __restrict__ Kb,
    const unsigned short* __restrict__ Vt, unsigned short* __restrict__ Ob) {
  __shared__ __align__(16) unsigned short Ks[32][136];   // keys x d (padded)
  __shared__ __align__(16) unsigned short Vs[128][40];   // d x keys (padded)
  __shared__ __align__(16) unsigned short Pb[4][16][40]; // per-wave P, q x keys (padded)

  const int tid = threadIdx.x;
  const int w = tid >> 6, lane = tid & 63;
  const int m = lane & 15, quad = lane >> 4;
  const int qb = blockIdx.x, bh = blockIdx.y;
  const int b = bh >> 5, h = bh & 31;

  const int rowA = qb * 64 + w * 16 + m;  // A-operand q row for this lane
  const size_t qoff = ((size_t)(b * S_LEN + rowA)) * 4096 + h * 128;

  bf16x8 qf[4];
#pragma unroll
  for (int kc = 0; kc < 4; ++kc) {
    B8U t; t.u = *reinterpret_cast<const uint4*>(Q + qoff + kc * 32 + quad * 8);
    qf[kc] = t.v;
  }

  floatx4 O[8] = {};
  float m_run[4], l_run[4], alpha[4];
#pragma unroll
  for (int r = 0; r < 4; ++r) { m_run[r] = -3e38f; l_run[r] = 0.0f; }

  const int kend = qb * 64 + 63;
  for (int k0 = 0; k0 <= kend; k0 += 32) {
    // stage K tile (32 keys x 128 d)
#pragma unroll
    for (int it = 0; it < 2; ++it) {
      int c = tid + it * 256;
      int key = c >> 4, d0 = (c & 15) * 8;
      uint4 val = *reinterpret_cast<const uint4*>(
          Kb + ((size_t)(b * S_LEN + k0 + key)) * 4096 + h * 128 + d0);
      *reinterpret_cast<uint4*>(&Ks[key][d0]) = val;
    }
    // stage V^T tile (128 d x 32 keys)
#pragma unroll
    for (int it = 0; it < 2; ++it) {
      int c = tid + it * 256;
      int d = c >> 2, kk = (c & 3) * 8;
      uint4 val = *reinterpret_cast<const uint4*>(
          Vt + ((size_t)bh * 128 + d) * S_LEN + k0 + kk);
      *reinterpret_cast<uint4*>(&Vs[d][kk]) = val;
    }
    __syncthreads();

    // scores: 16 q x 32 keys
    floatx4 s[2];
#pragma unroll
    for (int t16 = 0; t16 < 2; ++t16) {
      floatx4 a = {};
#pragma unroll
      for (int kc = 0; kc < 4; ++kc) {
        bf16x8 kf = lds_frag(&Ks[t16 * 16 + m][kc * 32 + quad * 8]);
        a = __builtin_amdgcn_mfma_f32_16x16x32_bf16(qf[kc], kf, a, 0, 0, 0);
      }
      s[t16] = a;
    }

    // causal mask + online softmax (exp2 domain; q pre-scaled by log2e/sqrt(HS))
#pragma unroll
    for (int r = 0; r < 4; ++r) {
      int rowD = qb * 64 + w * 16 + quad * 4 + r;
      float s0 = s[0][r]; if (k0 + m > rowD)      s0 = -3e38f;
      float s1 = s[1][r]; if (k0 + 16 + m > rowD) s1 = -3e38f;
      float mx = fmaxf(s0, s1);
#pragma unroll
      for (int off = 8; off > 0; off >>= 1) mx = fmaxf(mx, __shfl_xor(mx, off));
      float mn = fmaxf(m_run[r], mx);
      float al = exp2f(m_run[r] - mn);
      float p0 = exp2f(s0 - mn), p1 = exp2f(s1 - mn);
      float rs = p0 + p1;
#pragma unroll
      for (int off = 8; off > 0; off >>= 1) rs += __shfl_xor(rs, off);
      l_run[r] = l_run[r] * al + rs;
      m_run[r] = mn; alpha[r] = al;
      Pb[w][quad * 4 + r][m]      = f2bf(p0);
      Pb[w][quad * 4 + r][16 + m] = f2bf(p1);
    }

    // rescale O
#pragma unroll
    for (int nd = 0; nd < 8; ++nd)
#pragma unroll
      for (int r = 0; r < 4; ++r) O[nd][r] *= alpha[r];

    // P (A-layout) @ V
    bf16x8 pf = lds_frag(&Pb[w][m][quad * 8]);
#pragma unroll
    for (int nd = 0; nd < 8; ++nd) {
      bf16x8 vf = lds_frag(&Vs[nd * 16 + m][quad * 8]);
      O[nd] = __builtin_amdgcn_mfma_f32_16x16x32_bf16(pf, vf, O[nd], 0, 0, 0);
    }
    __syncthreads();
  }

#pragma unroll
  for (int r = 0; r < 4; ++r) {
    int rowD = qb * 64 + w * 16 + quad * 4 + r;
    float inv = 1.0f / l_run[r];
    size_t obase = ((size_t)(b * S_LEN + rowD)) * 4096 + h * 128;
#pragma unroll
    for (int nd = 0; nd < 8; ++nd)
      Ob[obase + nd * 16 + m] = f2bf(O[nd][r] * inv);
  }
}

// ---------------- launch ----------------
extern "C" void kernel_launch(void* const* d_in, const int* in_sizes, int n_in,
                              void* d_out, int out_size, void* d_ws, size_t ws_size,
                              hipStream_t stream) {
  const float* hidden  = (const float*)d_in[0];
  const float* cosb    = (const float*)d_in[1];
  const float* sinb    = (const float*)d_in[2];
  const float* w_qkv   = (const float*)d_in[3];
  const float* b_qkv   = (const float*)d_in[4];
  const float* w_dense = (const float*)d_in[5];
  const int*   slots   = (const int*)d_in[8];

  float* out = (float*)d_out;
  float* kvk = out + 16777216;
  float* kvv = out + 33554432;

  char* ws = (char*)d_ws;
  unsigned short* bfA = (unsigned short*)ws;                    // 33.5 MB (hidden bf16, later attn bf16)
  unsigned short* Wt  = (unsigned short*)(ws + 33554432);       // 100.7 MB (weights^T bf16, reused)
  float*          qkv = (float*)(ws + 134217728);               // 201.3 MB
  unsigned short* Qb  = (unsigned short*)(ws + 335544320);      // 33.5 MB
  unsigned short* Kb  = (unsigned short*)(ws + 369098752);      // 33.5 MB
  unsigned short* Vt  = (unsigned short*)(ws + 402653184);      // 33.5 MB  (total 436.2 MB)

  cast_bf16_kernel<<<16384, 256, 0, stream>>>(hidden, bfA, T_TOK * HIDN);
  tcast_kernel<<<dim3(NQKV / 32, HIDN / 32), dim3(32, 8), 0, stream>>>(w_qkv, Wt, HIDN, NQKV);
  gemm_bt<<<dim3(NQKV / 128, T_TOK / 128), 256, 0, stream>>>(bfA, Wt, b_qkv, qkv, T_TOK, NQKV, HIDN);
  rope_kernel<<<T_TOK, 256, 0, stream>>>(qkv, cosb, sinb, slots, Qb, Kb, kvk, kvv);
  vtrans_kernel<<<dim3(S_LEN / 32, HSZ / 32, 128), dim3(32, 8), 0, stream>>>(qkv, Vt);
  attn_kernel<<<dim3(S_LEN / 64, 128), 256, 0, stream>>>(Qb, Kb, Vt, bfA);
  tcast_kernel<<<dim3(HIDN / 32, HIDN / 32), dim3(32, 8), 0, stream>>>(w_dense, Wt, HIDN, HIDN);
  gemm_bt<<<dim3(HIDN / 128, T_TOK / 128), 256, 0, stream>>>(bfA, Wt, nullptr, out, T_TOK, HIDN, HIDN);
}